// Round 3
// baseline (202.472 us; speedup 1.0000x reference)
//
#include <hip/hip_runtime.h>
#include <hip/hip_bf16.h>

// MoE gate (DeepSeek-V2 style): logits = X @ W^T, softmax, group-limited
// top-3-of-8 groups, top-6 experts, normalized weights (sorted desc).
//
// X: [T=32768, H=2048] fp32   W: [64, 2048] fp32   out: [T, 6] fp32
//
// Precision: fp32 = hi+mid+lo bf16 (EXACT truncation split); 6 MFMA passes
// (hh, hm, mh, hl, lh, mm) -> ~1e-7 logit error (verified round 2, absmax 2e-3,
// 10x under threshold). W splits precomputed in d_ws (L2-resident).
//
// Round-3 change: K-SPLIT x4. 256-thread blocks, 4 waves each own a K-quarter
// (16 steps of K=32) for the same 32 tokens -> 4096 waves (4/SIMD, 50% occ)
// instead of 1024 (1/SIMD, latency-bound at 177us). Partial logits summed
// through LDS; epilogue parallel across waves (8 tokens each).

#define HD 2048
#define NE 64
#define KQ 512            // K per wave (2048/4)
#define NSTEP 16          // K-steps per wave (KQ/32)
#define LSTR 68           // LDS row stride (floats)

typedef __attribute__((ext_vector_type(4))) float f4;
typedef __attribute__((ext_vector_type(8))) short s8;
typedef __attribute__((ext_vector_type(4))) float accv;

struct B3 { s8 h, m, l; };

// Exact 3-way split of 8 fp32 into hi/mid/lo bf16 (truncation; residuals exact).
__device__ __forceinline__ void split8(const f4 v0, const f4 v1, s8& h, s8& m, s8& l) {
  float a[8] = {v0.x, v0.y, v0.z, v0.w, v1.x, v1.y, v1.z, v1.w};
  #pragma unroll
  for (int i = 0; i < 8; ++i) {
    unsigned u = __builtin_bit_cast(unsigned, a[i]);
    h[i] = (short)(u >> 16);
    float r1 = a[i] - __builtin_bit_cast(float, u & 0xffff0000u);
    unsigned u1 = __builtin_bit_cast(unsigned, r1);
    m[i] = (short)(u1 >> 16);
    float r2 = r1 - __builtin_bit_cast(float, u1 & 0xffff0000u);
    l[i] = (short)(__builtin_bit_cast(unsigned, r2) >> 16);
  }
}

// ---- kernel 1: split gate weights fp32 -> {hi,mid,lo} bf16 in d_ws --------
__global__ __launch_bounds__(256) void cvtW3(const float* __restrict__ Wf,
                                             unsigned short* __restrict__ Wh,
                                             unsigned short* __restrict__ Wm,
                                             unsigned short* __restrict__ Wl) {
  int i = (blockIdx.x * 256 + threadIdx.x) * 8;  // 64 blocks cover 131072
  f4 v0 = *(const f4*)(Wf + i);
  f4 v1 = *(const f4*)(Wf + i + 4);
  s8 h, m, l;
  split8(v0, v1, h, m, l);
  *(s8*)(Wh + i) = h;
  *(s8*)(Wm + i) = m;
  *(s8*)(Wl + i) = l;
}

template <bool PRE>
__device__ __forceinline__ B3 loadB(const float* __restrict__ Wf,
                                    const unsigned short* __restrict__ Wh,
                                    const unsigned short* __restrict__ Wm,
                                    const unsigned short* __restrict__ Wl,
                                    size_t base, int off) {
  B3 r;
  if constexpr (PRE) {
    r.h = *(const s8*)(Wh + base + off);
    r.m = *(const s8*)(Wm + base + off);
    r.l = *(const s8*)(Wl + base + off);
  } else {
    f4 v0 = *(const f4*)(Wf + base + off);
    f4 v1 = *(const f4*)(Wf + base + off + 4);
    split8(v0, v1, r.h, r.m, r.l);
  }
  return r;
}

__device__ __forceinline__ accv mfma6(s8 ah, s8 am, s8 al, const B3& b, accv t) {
  t = __builtin_amdgcn_mfma_f32_16x16x32_bf16(ah, b.h, t, 0, 0, 0);
  t = __builtin_amdgcn_mfma_f32_16x16x32_bf16(ah, b.m, t, 0, 0, 0);
  t = __builtin_amdgcn_mfma_f32_16x16x32_bf16(am, b.h, t, 0, 0, 0);
  t = __builtin_amdgcn_mfma_f32_16x16x32_bf16(ah, b.l, t, 0, 0, 0);
  t = __builtin_amdgcn_mfma_f32_16x16x32_bf16(al, b.h, t, 0, 0, 0);
  t = __builtin_amdgcn_mfma_f32_16x16x32_bf16(am, b.m, t, 0, 0, 0);
  return t;
}

// ---- kernel 2: fused gate, K-split x4 --------------------------------------
template <bool PRE>
__global__ __launch_bounds__(256, 4) void gate6(
    const float* __restrict__ X, const float* __restrict__ Wf,
    const unsigned short* __restrict__ Wh, const unsigned short* __restrict__ Wm,
    const unsigned short* __restrict__ Wl, float* __restrict__ out) {
  __shared__ float lds[4][32 * LSTR];  // per-wave partial logits: 32 tok x 64

  const int tid = threadIdx.x;
  const int lane = tid & 63;
  const int kq = tid >> 6;       // wave id = K-quarter 0..3
  const int c = lane & 15;       // token row (A) / expert col (B)
  const int kg = lane >> 4;      // 0..3, k-offset group (8 consecutive k)
  const int tok0 = blockIdx.x * 32;

  const float* pA0 = X + (size_t)(tok0 + c) * HD + kq * KQ + kg * 8;
  const float* pA1 = pA0 + (size_t)16 * HD;
  size_t bbase[4];
  #pragma unroll
  for (int f = 0; f < 4; ++f) bbase[f] = (size_t)(f * 16 + c) * HD + kq * KQ + kg * 8;

  accv acc[2][4];
  #pragma unroll
  for (int mf = 0; mf < 2; ++mf)
    #pragma unroll
    for (int f = 0; f < 4; ++f) acc[mf][f] = (accv){0.f, 0.f, 0.f, 0.f};

  // raw A double-buffer: [buf][mfrag][half]; B double-buffer
  f4 ar[2][2][2];
  B3 b[2][4];

  ar[0][0][0] = *(const f4*)(pA0 + 0);
  ar[0][0][1] = *(const f4*)(pA0 + 4);
  ar[0][1][0] = *(const f4*)(pA1 + 0);
  ar[0][1][1] = *(const f4*)(pA1 + 4);
  ar[1][0][0] = *(const f4*)(pA0 + 32);
  ar[1][0][1] = *(const f4*)(pA0 + 36);
  ar[1][1][0] = *(const f4*)(pA1 + 32);
  ar[1][1][1] = *(const f4*)(pA1 + 36);
  #pragma unroll
  for (int f = 0; f < 4; ++f) b[0][f] = loadB<PRE>(Wf, Wh, Wm, Wl, bbase[f], 0);

  for (int it = 0; it < NSTEP / 2; ++it) {
    const int s = 2 * it;
    // ===== even step s: consume ar[0], b[0] =====
    {
      s8 ah[2], am[2], al[2];
      #pragma unroll
      for (int mf = 0; mf < 2; ++mf) split8(ar[0][mf][0], ar[0][mf][1], ah[mf], am[mf], al[mf]);
      const int oA = (s + 2 < NSTEP ? s + 2 : NSTEP - 1) * 32;
      const int oB = (s + 1 < NSTEP ? s + 1 : NSTEP - 1) * 32;
      ar[0][0][0] = *(const f4*)(pA0 + oA);
      ar[0][0][1] = *(const f4*)(pA0 + oA + 4);
      ar[0][1][0] = *(const f4*)(pA1 + oA);
      ar[0][1][1] = *(const f4*)(pA1 + oA + 4);
      #pragma unroll
      for (int f = 0; f < 4; ++f) b[1][f] = loadB<PRE>(Wf, Wh, Wm, Wl, bbase[f], oB);
      #pragma unroll
      for (int mf = 0; mf < 2; ++mf)
        #pragma unroll
        for (int f = 0; f < 4; ++f)
          acc[mf][f] = mfma6(ah[mf], am[mf], al[mf], b[0][f], acc[mf][f]);
    }
    // ===== odd step s+1: consume ar[1], b[1] =====
    {
      s8 ah[2], am[2], al[2];
      #pragma unroll
      for (int mf = 0; mf < 2; ++mf) split8(ar[1][mf][0], ar[1][mf][1], ah[mf], am[mf], al[mf]);
      const int oA = (s + 3 < NSTEP ? s + 3 : NSTEP - 1) * 32;
      const int oB = (s + 2 < NSTEP ? s + 2 : NSTEP - 1) * 32;
      ar[1][0][0] = *(const f4*)(pA0 + oA);
      ar[1][0][1] = *(const f4*)(pA0 + oA + 4);
      ar[1][1][0] = *(const f4*)(pA1 + oA);
      ar[1][1][1] = *(const f4*)(pA1 + oA + 4);
      #pragma unroll
      for (int f = 0; f < 4; ++f) b[0][f] = loadB<PRE>(Wf, Wh, Wm, Wl, bbase[f], oB);
      #pragma unroll
      for (int mf = 0; mf < 2; ++mf)
        #pragma unroll
        for (int f = 0; f < 4; ++f)
          acc[mf][f] = mfma6(ah[mf], am[mf], al[mf], b[1][f], acc[mf][f]);
    }
  }

  // --- scatter partial logits: C/D layout col=lane&15, row=(lane>>4)*4+r ---
  #pragma unroll
  for (int mf = 0; mf < 2; ++mf)
    #pragma unroll
    for (int f = 0; f < 4; ++f)
      #pragma unroll
      for (int r = 0; r < 4; ++r)
        lds[kq][(mf * 16 + kg * 4 + r) * LSTR + f * 16 + c] = acc[mf][f][r];
  __syncthreads();

  // --- per-token epilogue: 8 tokens per wave, lanes 0..7 ---
  if (lane < 8) {
    const int t = kq * 8 + lane;
    float v[64];
    #pragma unroll
    for (int i = 0; i < 16; ++i) {
      f4 q0 = *(const f4*)(&lds[0][t * LSTR + 4 * i]);
      f4 q1 = *(const f4*)(&lds[1][t * LSTR + 4 * i]);
      f4 q2 = *(const f4*)(&lds[2][t * LSTR + 4 * i]);
      f4 q3 = *(const f4*)(&lds[3][t * LSTR + 4 * i]);
      f4 q = (q0 + q1) + (q2 + q3);
      v[4 * i + 0] = q.x; v[4 * i + 1] = q.y;
      v[4 * i + 2] = q.z; v[4 * i + 3] = q.w;
    }
    // group maxes on logits (softmax monotonic -> same selection)
    float gm[8];
    #pragma unroll
    for (int g = 0; g < 8; ++g) {
      float mx = v[g * 8];
      #pragma unroll
      for (int j = 1; j < 8; ++j) mx = fmaxf(mx, v[g * 8 + j]);
      gm[g] = mx;
    }
    // top-3 groups, ties -> lowest index (matches lax.top_k)
    unsigned selmask = 0u;
    #pragma unroll
    for (int itg = 0; itg < 3; ++itg) {
      float best = gm[0];
      #pragma unroll
      for (int g = 1; g < 8; ++g) best = fmaxf(best, gm[g]);
      int bi = 7;
      #pragma unroll
      for (int g = 6; g >= 0; --g)
        if (gm[g] == best) bi = g;
      selmask |= (1u << bi);
      #pragma unroll
      for (int g = 0; g < 8; ++g) gm[g] = (g == bi) ? -3.0e38f : gm[g];
    }
    // top-6 of selected-group logits, branchless insertion network (sorted desc)
    float t0 = -3.0e38f, t1 = -3.0e38f, t2 = -3.0e38f;
    float t3 = -3.0e38f, t4 = -3.0e38f, t5 = -3.0e38f;
    #pragma unroll
    for (int g = 0; g < 8; ++g) {
      const bool sel = (selmask >> g) & 1u;
      #pragma unroll
      for (int j = 0; j < 8; ++j) {
        float x = sel ? v[g * 8 + j] : -3.0e38f;
        float mm;
        mm = fmaxf(t0, x); x = fminf(t0, x); t0 = mm;
        mm = fmaxf(t1, x); x = fminf(t1, x); t1 = mm;
        mm = fmaxf(t2, x); x = fminf(t2, x); t2 = mm;
        mm = fmaxf(t3, x); x = fminf(t3, x); t3 = mm;
        mm = fmaxf(t4, x); x = fminf(t4, x); t4 = mm;
        t5 = fmaxf(t5, x);
      }
    }
    // normalized softmax over the selected 6 (global denom cancels exactly)
    float e0 = 1.0f;
    float e1 = __expf(t1 - t0);
    float e2 = __expf(t2 - t0);
    float e3 = __expf(t3 - t0);
    float e4 = __expf(t4 - t0);
    float e5 = __expf(t5 - t0);
    float sum = e0 + e1 + e2 + e3 + e4 + e5;
    float inv = 1.0f / sum;
    float* op = out + (size_t)(tok0 + t) * 6;
    op[0] = e0 * inv; op[1] = e1 * inv; op[2] = e2 * inv;
    op[3] = e3 * inv; op[4] = e4 * inv; op[5] = e5 * inv;
  }
}

extern "C" void kernel_launch(void* const* d_in, const int* in_sizes, int n_in,
                              void* d_out, int out_size, void* d_ws, size_t ws_size,
                              hipStream_t stream) {
  const float* X = (const float*)d_in[0];
  const float* Wf = (const float*)d_in[1];
  float* out = (float*)d_out;
  const int T = in_sizes[0] / HD;  // 32768
  const int nblk = T / 32;         // 1024 blocks of 256 threads (4 waves)

  const size_t need = (size_t)NE * HD * sizeof(unsigned short);  // 256 KB per split
  if (ws_size >= 3 * need) {
    unsigned short* Whi = (unsigned short*)d_ws;
    unsigned short* Wmi = Whi + (size_t)NE * HD;
    unsigned short* Wlo = Wmi + (size_t)NE * HD;
    cvtW3<<<dim3(64), dim3(256), 0, stream>>>(Wf, Whi, Wmi, Wlo);
    gate6<true><<<dim3(nblk), dim3(256), 0, stream>>>(X, Wf, Whi, Wmi, Wlo, out);
  } else {
    gate6<false><<<dim3(nblk), dim3(256), 0, stream>>>(X, Wf, nullptr, nullptr, nullptr, out);
  }
}

// Round 4
// 125.176 us; speedup vs baseline: 1.6175x; 1.6175x over previous
//
#include <hip/hip_runtime.h>
#include <hip/hip_bf16.h>

// MoE gate (DeepSeek-V2 style): logits = X @ W^T, softmax, group-limited
// top-3-of-8 groups, top-6 experts, normalized weights (sorted desc).
//
// X: [T=32768, H=2048] fp32   W: [64, 2048] fp32   out: [T, 6] fp32
//
// Precision: fp32 = hi+mid+lo bf16 (EXACT truncation split); 6 MFMA passes
// (hh, hm, mh, hl, lh, mm) -> ~1e-7 logit error (verified r2/r3, absmax 2e-3).
//
// Round-4 change: N-SPLIT (was K-split). 256-thr blocks, 32 tokens/block;
// each of 4 waves owns 16 EXPERTS (1 N-frag) over full K -> B working set
// 24 VGPR (was 96; r3 spilled 136 MB of scratch at the (256,4) 128-reg cap).
// A tile split ONCE into LDS cooperatively (f4 load -> 3-way split ->
// ds_write_b64), double-buffered, 1 barrier/step. ~90 VGPR total -> no spill,
// 4 blocks/CU. Logits partitioned by expert -> no cross-wave reduction.

#define HD 2048
#define NE 64
#define TPB 32      // tokens per block
#define NSTEP 64    // K-steps of 32 (2048/32)
#define ABUF 3072   // ushorts per A buffer: 3 splits * 4 kg * 32 tok * 8

typedef __attribute__((ext_vector_type(4))) float f4;
typedef __attribute__((ext_vector_type(8))) short s8;
typedef __attribute__((ext_vector_type(4))) short s4;
typedef __attribute__((ext_vector_type(4))) float accv;

struct B3 { s8 h, m, l; };

// Exact 3-way split of 4 fp32 into hi/mid/lo bf16 (truncation; residuals exact).
__device__ __forceinline__ void split4(const f4 v, s4& h, s4& m, s4& l) {
  #pragma unroll
  for (int i = 0; i < 4; ++i) {
    float a = v[i];
    unsigned u = __builtin_bit_cast(unsigned, a);
    h[i] = (short)(u >> 16);
    float r1 = a - __builtin_bit_cast(float, u & 0xffff0000u);
    unsigned u1 = __builtin_bit_cast(unsigned, r1);
    m[i] = (short)(u1 >> 16);
    float r2 = r1 - __builtin_bit_cast(float, u1 & 0xffff0000u);
    l[i] = (short)(__builtin_bit_cast(unsigned, r2) >> 16);
  }
}

__device__ __forceinline__ void split8(const f4 v0, const f4 v1, s8& h, s8& m, s8& l) {
  s4 h0, m0, l0, h1, m1, l1;
  split4(v0, h0, m0, l0);
  split4(v1, h1, m1, l1);
  #pragma unroll
  for (int i = 0; i < 4; ++i) {
    h[i] = h0[i]; h[i + 4] = h1[i];
    m[i] = m0[i]; m[i + 4] = m1[i];
    l[i] = l0[i]; l[i + 4] = l1[i];
  }
}

// ---- kernel 1: split gate weights fp32 -> {hi,mid,lo} bf16 in d_ws --------
__global__ __launch_bounds__(256) void cvtW3(const float* __restrict__ Wf,
                                             unsigned short* __restrict__ Wh,
                                             unsigned short* __restrict__ Wm,
                                             unsigned short* __restrict__ Wl) {
  int i = (blockIdx.x * 256 + threadIdx.x) * 8;  // 64 blocks cover 131072
  f4 v0 = *(const f4*)(Wf + i);
  f4 v1 = *(const f4*)(Wf + i + 4);
  s8 h, m, l;
  split8(v0, v1, h, m, l);
  *(s8*)((short*)Wh + i) = h;
  *(s8*)((short*)Wm + i) = m;
  *(s8*)((short*)Wl + i) = l;
}

template <bool PRE>
__device__ __forceinline__ B3 loadB(const float* __restrict__ Wf,
                                    const unsigned short* __restrict__ Wh,
                                    const unsigned short* __restrict__ Wm,
                                    const unsigned short* __restrict__ Wl,
                                    size_t base, int off) {
  B3 r;
  if constexpr (PRE) {
    r.h = *(const s8*)(Wh + base + off);
    r.m = *(const s8*)(Wm + base + off);
    r.l = *(const s8*)(Wl + base + off);
  } else {
    f4 v0 = *(const f4*)(Wf + base + off);
    f4 v1 = *(const f4*)(Wf + base + off + 4);
    split8(v0, v1, r.h, r.m, r.l);
  }
  return r;
}

__device__ __forceinline__ accv mfma6(s8 ah, s8 am, s8 al, const B3& b, accv t) {
  t = __builtin_amdgcn_mfma_f32_16x16x32_bf16(ah, b.h, t, 0, 0, 0);
  t = __builtin_amdgcn_mfma_f32_16x16x32_bf16(ah, b.m, t, 0, 0, 0);
  t = __builtin_amdgcn_mfma_f32_16x16x32_bf16(am, b.h, t, 0, 0, 0);
  t = __builtin_amdgcn_mfma_f32_16x16x32_bf16(ah, b.l, t, 0, 0, 0);
  t = __builtin_amdgcn_mfma_f32_16x16x32_bf16(al, b.h, t, 0, 0, 0);
  t = __builtin_amdgcn_mfma_f32_16x16x32_bf16(am, b.m, t, 0, 0, 0);
  return t;
}

// ---- kernel 2: fused gate, N-split x4 with LDS-staged split-once A --------
template <bool PRE>
__global__ __launch_bounds__(256, 4) void gateN(
    const float* __restrict__ X, const float* __restrict__ Wf,
    const unsigned short* __restrict__ Wh, const unsigned short* __restrict__ Wm,
    const unsigned short* __restrict__ Wl, float* __restrict__ out) {
  // A split-tiles: [buf][split][kg 0..3][tok 0..31][8 bf16] = 12 KB; the same
  // region is reused as float logits [32][68] (8704 B) in the epilogue.
  __shared__ __align__(16) unsigned short smem[2 * ABUF];

  const int tid = threadIdx.x;
  const int lane = tid & 63;
  const int w = tid >> 6;  // wave id 0..3 = expert group
  const int tok0 = blockIdx.x * TPB;

  // --- staging mapping: thread -> (token, 4-k slice) ---
  const int stok = tid >> 3;  // 0..31
  const int sk4 = tid & 7;    // 0..7  (k = sk4*4 .. +4 within the 32-k step)
  const int wbase = (sk4 >> 1) * 256 + stok * 8 + (sk4 & 1) * 4;  // ushorts
  const float* pX = X + (size_t)(tok0 + stok) * HD + sk4 * 4;

  // --- reader mapping: MFMA fragments ---
  const int ec = lane & 15;  // expert-in-frag (B col) / token row (A)
  const int kg = lane >> 4;  // 0..3 (8 consecutive k)
  const size_t bb = (size_t)(w * 16 + ec) * HD + kg * 8;

  accv acc[2];
  acc[0] = (accv){0.f, 0.f, 0.f, 0.f};
  acc[1] = (accv){0.f, 0.f, 0.f, 0.f};

  // --- prologue: load step0+step1 A, write step0 into buf0, load B(0) ---
  f4 a_pend = *(const f4*)(pX);
  f4 a_fly = *(const f4*)(pX + 32);
  {
    s4 h, m, l;
    split4(a_pend, h, m, l);
    unsigned short* p = smem + wbase;
    *(s4*)(p) = h;
    *(s4*)(p + 1024) = m;
    *(s4*)(p + 2048) = l;
  }
  a_pend = a_fly;
  B3 bc = loadB<PRE>(Wf, Wh, Wm, Wl, bb, 0);
  __syncthreads();  // buf0 ready

  #pragma unroll 2
  for (int s = 0; s < NSTEP; ++s) {
    // stage step s+1 (in a_pend) into buf[(s+1)&1]
    {
      s4 h, m, l;
      split4(a_pend, h, m, l);
      unsigned short* p = smem + ((s + 1) & 1) * ABUF + wbase;
      *(s4*)(p) = h;
      *(s4*)(p + 1024) = m;
      *(s4*)(p + 2048) = l;
    }
    // issue A load for step s+2, B load for step s+1 (clamped; dup harmless)
    const int nA = (s + 2 < NSTEP ? s + 2 : NSTEP - 1) * 32;
    const int nB = (s + 1 < NSTEP ? s + 1 : NSTEP - 1) * 32;
    a_pend = *(const f4*)(pX + nA);
    B3 bn = loadB<PRE>(Wf, Wh, Wm, Wl, bb, nB);

    // compute step s from buf[s&1]
    const unsigned short* q = smem + (s & 1) * ABUF;
    #pragma unroll
    for (int mf = 0; mf < 2; ++mf) {
      const int ro = kg * 256 + (ec + mf * 16) * 8;
      s8 ah = *(const s8*)(q + ro);
      s8 am = *(const s8*)(q + 1024 + ro);
      s8 al = *(const s8*)(q + 2048 + ro);
      acc[mf] = mfma6(ah, am, al, bc, acc[mf]);
    }
    __syncthreads();
    bc = bn;
  }

  // --- merge logits through LDS (region reuse; barrier above protects) ---
  float* llog = (float*)smem;  // [32 tok][68]
  #pragma unroll
  for (int mf = 0; mf < 2; ++mf)
    #pragma unroll
    for (int r = 0; r < 4; ++r)
      llog[(mf * 16 + kg * 4 + r) * 68 + w * 16 + ec] = acc[mf][r];
  __syncthreads();

  // --- per-token epilogue: 8 tokens per wave, lanes 0..7 ---
  if (lane < 8) {
    const int t = w * 8 + lane;
    float v[64];
    #pragma unroll
    for (int i = 0; i < 16; ++i) {
      f4 q = *(const f4*)(llog + t * 68 + 4 * i);
      v[4 * i + 0] = q.x; v[4 * i + 1] = q.y;
      v[4 * i + 2] = q.z; v[4 * i + 3] = q.w;
    }
    // group maxes on logits (softmax monotonic -> same selection)
    float gm[8];
    #pragma unroll
    for (int g = 0; g < 8; ++g) {
      float mx = v[g * 8];
      #pragma unroll
      for (int j = 1; j < 8; ++j) mx = fmaxf(mx, v[g * 8 + j]);
      gm[g] = mx;
    }
    // top-3 groups, ties -> lowest index (matches lax.top_k)
    unsigned selmask = 0u;
    #pragma unroll
    for (int itg = 0; itg < 3; ++itg) {
      float best = gm[0];
      #pragma unroll
      for (int g = 1; g < 8; ++g) best = fmaxf(best, gm[g]);
      int bi = 7;
      #pragma unroll
      for (int g = 6; g >= 0; --g)
        if (gm[g] == best) bi = g;
      selmask |= (1u << bi);
      #pragma unroll
      for (int g = 0; g < 8; ++g) gm[g] = (g == bi) ? -3.0e38f : gm[g];
    }
    // top-6 of selected-group logits, branchless insertion network (sorted desc)
    float t0 = -3.0e38f, t1 = -3.0e38f, t2 = -3.0e38f;
    float t3 = -3.0e38f, t4 = -3.0e38f, t5 = -3.0e38f;
    #pragma unroll
    for (int g = 0; g < 8; ++g) {
      const bool sel = (selmask >> g) & 1u;
      #pragma unroll
      for (int j = 0; j < 8; ++j) {
        float x = sel ? v[g * 8 + j] : -3.0e38f;
        float mm;
        mm = fmaxf(t0, x); x = fminf(t0, x); t0 = mm;
        mm = fmaxf(t1, x); x = fminf(t1, x); t1 = mm;
        mm = fmaxf(t2, x); x = fminf(t2, x); t2 = mm;
        mm = fmaxf(t3, x); x = fminf(t3, x); t3 = mm;
        mm = fmaxf(t4, x); x = fminf(t4, x); t4 = mm;
        t5 = fmaxf(t5, x);
      }
    }
    // normalized softmax over the selected 6 (global denom cancels exactly)
    float e0 = 1.0f;
    float e1 = __expf(t1 - t0);
    float e2 = __expf(t2 - t0);
    float e3 = __expf(t3 - t0);
    float e4 = __expf(t4 - t0);
    float e5 = __expf(t5 - t0);
    float sum = e0 + e1 + e2 + e3 + e4 + e5;
    float inv = 1.0f / sum;
    float* op = out + (size_t)(tok0 + t) * 6;
    op[0] = e0 * inv; op[1] = e1 * inv; op[2] = e2 * inv;
    op[3] = e3 * inv; op[4] = e4 * inv; op[5] = e5 * inv;
  }
}

extern "C" void kernel_launch(void* const* d_in, const int* in_sizes, int n_in,
                              void* d_out, int out_size, void* d_ws, size_t ws_size,
                              hipStream_t stream) {
  const float* X = (const float*)d_in[0];
  const float* Wf = (const float*)d_in[1];
  float* out = (float*)d_out;
  const int T = in_sizes[0] / HD;  // 32768
  const int nblk = T / TPB;        // 1024 blocks of 256 threads (4 waves)

  const size_t need = (size_t)NE * HD * sizeof(unsigned short);  // 256 KB per split
  if (ws_size >= 3 * need) {
    unsigned short* Whi = (unsigned short*)d_ws;
    unsigned short* Wmi = Whi + (size_t)NE * HD;
    unsigned short* Wlo = Wmi + (size_t)NE * HD;
    cvtW3<<<dim3(64), dim3(256), 0, stream>>>(Wf, Whi, Wmi, Wlo);
    gateN<true><<<dim3(nblk), dim3(256), 0, stream>>>(X, Wf, Whi, Wmi, Wlo, out);
  } else {
    gateN<false><<<dim3(nblk), dim3(256), 0, stream>>>(X, Wf, nullptr, nullptr, nullptr, out);
  }
}

// Round 5
// 89.215 us; speedup vs baseline: 2.2695x; 1.4031x over previous
//
#include <hip/hip_runtime.h>
#include <hip/hip_bf16.h>

// MoE gate (DeepSeek-V2 style): logits = X @ W^T, softmax, group-limited
// top-3-of-8 groups, top-6 experts, normalized weights (sorted desc).
//
// X: [T=32768, H=2048] fp32   W: [64, 2048] fp32   out: [T, 6] fp32
//
// Precision: fp32 = hi+mid+lo bf16 (EXACT truncation split); 6 MFMA passes
// (hh, hm, mh, hl, lh, mm) -> ~1e-7 logit error (verified r2-r4, absmax 2e-3).
//
// Round-5 structure (fixes r4's latency exposure):
//  - 512-thr blocks (8 waves), 128 tokens/block, 256 blocks (1/CU).
//  - B (weights, L2-hot) staged into LDS in K-64 double-buffered chunks;
//    each wave stages one (step, expert-group) unit: loads issued at chunk
//    TOP, ds_write at chunk BOTTOM (T14 issue-early/write-late).
//  - A (X, the 268MB HBM stream) direct global->reg, 2-step prefetch.
//  - Chunk boundary: sched_barrier + s_waitcnt lgkmcnt(0) + raw s_barrier:
//    NO vmcnt drain -> A prefetch stays in flight across barriers.
//  - B LDS layout: slot = lane*16B -> stride-1 ds_read_b128, 0 conflicts.

#define HD 2048
#define NE 64
#define NCH 32       // K-chunks of 64
#define BUFB 24576   // bytes per LDS B buffer (2 steps * 3 splits * 4KB)

typedef __attribute__((ext_vector_type(4))) float f4;
typedef __attribute__((ext_vector_type(8))) short s8;
typedef __attribute__((ext_vector_type(4))) short s4;
typedef __attribute__((ext_vector_type(4))) float accv;
typedef unsigned short u16;

// Exact 3-way split of fp32 into hi/mid/lo bf16 (truncation; residuals exact).
__device__ __forceinline__ void split4(const f4 v, s4& h, s4& m, s4& l) {
  #pragma unroll
  for (int i = 0; i < 4; ++i) {
    float a = v[i];
    unsigned u = __builtin_bit_cast(unsigned, a);
    h[i] = (short)(u >> 16);
    float r1 = a - __builtin_bit_cast(float, u & 0xffff0000u);
    unsigned u1 = __builtin_bit_cast(unsigned, r1);
    m[i] = (short)(u1 >> 16);
    float r2 = r1 - __builtin_bit_cast(float, u1 & 0xffff0000u);
    l[i] = (short)(__builtin_bit_cast(unsigned, r2) >> 16);
  }
}

__device__ __forceinline__ void split8(const f4 v0, const f4 v1, s8& h, s8& m, s8& l) {
  s4 h0, m0, l0, h1, m1, l1;
  split4(v0, h0, m0, l0);
  split4(v1, h1, m1, l1);
  #pragma unroll
  for (int i = 0; i < 4; ++i) {
    h[i] = h0[i]; h[i + 4] = h1[i];
    m[i] = m0[i]; m[i + 4] = m1[i];
    l[i] = l0[i]; l[i + 4] = l1[i];
  }
}

// ---- kernel 1: split gate weights fp32 -> {hi,mid,lo} bf16 in d_ws --------
__global__ __launch_bounds__(256) void cvtW3(const float* __restrict__ Wf,
                                             u16* __restrict__ Wh,
                                             u16* __restrict__ Wm,
                                             u16* __restrict__ Wl) {
  int i = (blockIdx.x * 256 + threadIdx.x) * 8;  // 64 blocks cover 131072
  f4 v0 = *(const f4*)(Wf + i);
  f4 v1 = *(const f4*)(Wf + i + 4);
  s8 h, m, l;
  split8(v0, v1, h, m, l);
  *(s8*)((short*)Wh + i) = h;
  *(s8*)((short*)Wm + i) = m;
  *(s8*)((short*)Wl + i) = l;
}

// ---- kernel 2: fused gate ---------------------------------------------------
template <bool PRE>
__global__ __launch_bounds__(512, 2) void gateL(
    const float* __restrict__ X, const float* __restrict__ Wf,
    const u16* __restrict__ Wh, const u16* __restrict__ Wm,
    const u16* __restrict__ Wl, float* __restrict__ out) {
  __shared__ __align__(16) unsigned char smem[2 * BUFB];  // 48 KB

  const int tid = threadIdx.x;
  const int lane = tid & 63;
  const int w = tid >> 6;      // wave 0..7 -> owns tokens tok0 + w*16 ..
  const int ec = lane & 15;    // token row (A) / expert col (B)
  const int kg = lane >> 4;    // 0..3 (8 consecutive k)
  const int tok0 = blockIdx.x * 128;

  // A stream: this wave's 16 token rows
  const float* pA = X + (size_t)(tok0 + w * 16 + ec) * HD + kg * 8;

  // staging role: wave w stages unit (step sh, expert-group sg), all 3 splits
  const int sg = w & 3;
  const int sh = w >> 2;  // step-in-chunk 0..1
  const size_t wsrc = (size_t)(sg * 16 + ec) * HD + sh * 32 + kg * 8;
  // LDS dst byte offset within a buffer: ((sh*3+split)*4+sg)*1024 + lane*16
  const int sdst = (sh * 3 * 4 + sg) * 1024 + lane * 16;  // split 0; +4096/split

  accv acc[4];
  #pragma unroll
  for (int f = 0; f < 4; ++f) acc[f] = (accv){0.f, 0.f, 0.f, 0.f};

  f4 ar[2][2];  // A raw, 2-step ring (static indices only)

  // --- prologue: stage chunk 0 into buf0; prefetch A t=0,1 ---
  {
    s8 th, tm, tl;
    if constexpr (PRE) {
      th = *(const s8*)(Wh + wsrc);
      tm = *(const s8*)(Wm + wsrc);
      tl = *(const s8*)(Wl + wsrc);
    } else {
      f4 r0 = *(const f4*)(Wf + wsrc);
      f4 r1 = *(const f4*)(Wf + wsrc + 4);
      split8(r0, r1, th, tm, tl);
    }
    unsigned char* d = smem + sdst;
    *(s8*)(d) = th;
    *(s8*)(d + 4096) = tm;
    *(s8*)(d + 8192) = tl;
  }
  ar[0][0] = *(const f4*)(pA + 0);
  ar[0][1] = *(const f4*)(pA + 4);
  ar[1][0] = *(const f4*)(pA + 32);
  ar[1][1] = *(const f4*)(pA + 36);
  asm volatile("s_waitcnt lgkmcnt(0)");
  __builtin_amdgcn_s_barrier();
  __builtin_amdgcn_sched_barrier(0);

  // --- main loop: 32 chunks of K=64 (2 MFMA-steps each) ---
  for (int c = 0; c < NCH; ++c) {
    const unsigned char* rb = smem + (c & 1) * BUFB;
    unsigned char* wb = smem + ((c + 1) & 1) * BUFB;
    const bool do_stage = (c + 1 < NCH);

    // issue next-chunk B loads NOW (written to LDS after compute: T14 split)
    s8 th, tm, tl;
    f4 r0, r1;
    if (do_stage) {
      const size_t o = wsrc + (size_t)(c + 1) * 64;
      if constexpr (PRE) {
        th = *(const s8*)(Wh + o);
        tm = *(const s8*)(Wm + o);
        tl = *(const s8*)(Wl + o);
      } else {
        r0 = *(const f4*)(Wf + o);
        r1 = *(const f4*)(Wf + o + 4);
      }
    }

    #pragma unroll
    for (int st = 0; st < 2; ++st) {
      const int t = c * 2 + st;
      s8 ah, am, al;
      split8(ar[st][0], ar[st][1], ah, am, al);
      const int tn = (t + 2 < 64) ? (t + 2) : 63;  // clamp; dup load harmless
      ar[st][0] = *(const f4*)(pA + tn * 32);
      ar[st][1] = *(const f4*)(pA + tn * 32 + 4);
      #pragma unroll
      for (int f = 0; f < 4; ++f) {
        const unsigned char* bp = rb + st * 12288 + f * 1024 + lane * 16;
        s8 bh = *(const s8*)(bp);
        s8 bm = *(const s8*)(bp + 4096);
        s8 bl = *(const s8*)(bp + 8192);
        acc[f] = __builtin_amdgcn_mfma_f32_16x16x32_bf16(ah, bh, acc[f], 0, 0, 0);
        acc[f] = __builtin_amdgcn_mfma_f32_16x16x32_bf16(ah, bm, acc[f], 0, 0, 0);
        acc[f] = __builtin_amdgcn_mfma_f32_16x16x32_bf16(am, bh, acc[f], 0, 0, 0);
        acc[f] = __builtin_amdgcn_mfma_f32_16x16x32_bf16(ah, bl, acc[f], 0, 0, 0);
        acc[f] = __builtin_amdgcn_mfma_f32_16x16x32_bf16(al, bh, acc[f], 0, 0, 0);
        acc[f] = __builtin_amdgcn_mfma_f32_16x16x32_bf16(am, bm, acc[f], 0, 0, 0);
      }
    }

    // write staged B (loads have had ~2 steps to land)
    if (do_stage) {
      if constexpr (!PRE) split8(r0, r1, th, tm, tl);
      unsigned char* d = wb + sdst;
      *(s8*)(d) = th;
      *(s8*)(d + 4096) = tm;
      *(s8*)(d + 8192) = tl;
    }
    // boundary: LDS-only drain; A vmcnt stream NEVER drained
    __builtin_amdgcn_sched_barrier(0);
    asm volatile("s_waitcnt lgkmcnt(0)");
    __builtin_amdgcn_s_barrier();
    __builtin_amdgcn_sched_barrier(0);
  }

  // --- epilogue: per-wave logit scatter (own region, no barrier needed) ---
  float* lf = (float*)smem + w * 1088;  // 16 tok x 68 floats
  #pragma unroll
  for (int f = 0; f < 4; ++f)
    #pragma unroll
    for (int r = 0; r < 4; ++r)
      lf[(kg * 4 + r) * 68 + f * 16 + ec] = acc[f][r];

  if (lane < 16) {
    float v[64];
    #pragma unroll
    for (int i = 0; i < 16; ++i) {
      f4 q = *(const f4*)(lf + lane * 68 + 4 * i);
      v[4 * i + 0] = q.x; v[4 * i + 1] = q.y;
      v[4 * i + 2] = q.z; v[4 * i + 3] = q.w;
    }
    // group maxes on logits (softmax monotonic -> same selection)
    float gm[8];
    #pragma unroll
    for (int g = 0; g < 8; ++g) {
      float mx = v[g * 8];
      #pragma unroll
      for (int j = 1; j < 8; ++j) mx = fmaxf(mx, v[g * 8 + j]);
      gm[g] = mx;
    }
    // top-3 groups, ties -> lowest index (matches lax.top_k)
    unsigned selmask = 0u;
    #pragma unroll
    for (int itg = 0; itg < 3; ++itg) {
      float best = gm[0];
      #pragma unroll
      for (int g = 1; g < 8; ++g) best = fmaxf(best, gm[g]);
      int bi = 7;
      #pragma unroll
      for (int g = 6; g >= 0; --g)
        if (gm[g] == best) bi = g;
      selmask |= (1u << bi);
      #pragma unroll
      for (int g = 0; g < 8; ++g) gm[g] = (g == bi) ? -3.0e38f : gm[g];
    }
    // top-6 of selected-group logits, branchless insertion network (desc)
    float t0 = -3.0e38f, t1 = -3.0e38f, t2 = -3.0e38f;
    float t3 = -3.0e38f, t4 = -3.0e38f, t5 = -3.0e38f;
    #pragma unroll
    for (int g = 0; g < 8; ++g) {
      const bool sel = (selmask >> g) & 1u;
      #pragma unroll
      for (int j = 0; j < 8; ++j) {
        float x = sel ? v[g * 8 + j] : -3.0e38f;
        float mm;
        mm = fmaxf(t0, x); x = fminf(t0, x); t0 = mm;
        mm = fmaxf(t1, x); x = fminf(t1, x); t1 = mm;
        mm = fmaxf(t2, x); x = fminf(t2, x); t2 = mm;
        mm = fmaxf(t3, x); x = fminf(t3, x); t3 = mm;
        mm = fmaxf(t4, x); x = fminf(t4, x); t4 = mm;
        t5 = fmaxf(t5, x);
      }
    }
    // normalized softmax over the selected 6 (global denom cancels exactly)
    float e0 = 1.0f;
    float e1 = __expf(t1 - t0);
    float e2 = __expf(t2 - t0);
    float e3 = __expf(t3 - t0);
    float e4 = __expf(t4 - t0);
    float e5 = __expf(t5 - t0);
    float sum = e0 + e1 + e2 + e3 + e4 + e5;
    float inv = 1.0f / sum;
    float* op = out + (size_t)(tok0 + w * 16 + lane) * 6;
    op[0] = e0 * inv; op[1] = e1 * inv; op[2] = e2 * inv;
    op[3] = e3 * inv; op[4] = e4 * inv; op[5] = e5 * inv;
  }
}

extern "C" void kernel_launch(void* const* d_in, const int* in_sizes, int n_in,
                              void* d_out, int out_size, void* d_ws, size_t ws_size,
                              hipStream_t stream) {
  const float* X = (const float*)d_in[0];
  const float* Wf = (const float*)d_in[1];
  float* out = (float*)d_out;
  const int T = in_sizes[0] / HD;  // 32768
  const int nblk = T / 128;        // 256 blocks of 512 threads (8 waves)

  const size_t need = (size_t)NE * HD * sizeof(u16);  // 256 KB per split
  if (ws_size >= 3 * need) {
    u16* Whi = (u16*)d_ws;
    u16* Wmi = Whi + (size_t)NE * HD;
    u16* Wlo = Wmi + (size_t)NE * HD;
    cvtW3<<<dim3(64), dim3(256), 0, stream>>>(Wf, Whi, Wmi, Wlo);
    gateL<true><<<dim3(nblk), dim3(512), 0, stream>>>(X, Wf, Whi, Wmi, Wlo, out);
  } else {
    gateL<false><<<dim3(nblk), dim3(512), 0, stream>>>(X, Wf, nullptr, nullptr, nullptr, out);
  }
}

// Round 6
// 79.738 us; speedup vs baseline: 2.5392x; 1.1189x over previous
//
#include <hip/hip_runtime.h>
#include <hip/hip_bf16.h>

// MoE gate (DeepSeek-V2 style): logits = X @ W^T, softmax, group-limited
// top-3-of-8 groups, top-6 experts, normalized weights (sorted desc).
//
// X: [T=32768, H=2048] fp32   W: [64, 2048] fp32   out: [T, 6] fp32
//
// Precision: fp32 = hi+mid+lo bf16 (EXACT truncation split); 6 MFMA passes
// (hh, hm, mh, hl, lh, mm) -> ~1e-7 logit error (verified r2-r5, absmax 2e-3).
//
// Round-6 changes vs r5 (89us, still latency-exposed):
//  - A register ring deepened 2 -> 4 steps (~1600cyc lookahead vs ~900 HBM).
//  - Chunks widened K-64 -> K-128 (4 MFMA-steps between barriers; half the
//    block-wide sync points; B stage-loads get 4 steps to land).
//  - Everything else identical: B (L2-hot) staged to LDS double-buffered,
//    issue-early/write-late; A never vmcnt-drained; lane*16B LDS slots
//    (stride-1 ds_read_b128, 0 conflicts); 512-thr blocks, 128 tok, 256 blks.

#define HD 2048
#define NE 64
#define NCH 16       // K-chunks of 128
#define SPC 4        // MFMA-steps (K=32) per chunk
#define BUFB 49152   // bytes per LDS B buffer (4 steps * 3 splits * 4KB)

typedef __attribute__((ext_vector_type(4))) float f4;
typedef __attribute__((ext_vector_type(8))) short s8;
typedef __attribute__((ext_vector_type(4))) short s4;
typedef __attribute__((ext_vector_type(4))) float accv;
typedef unsigned short u16;

// Exact 3-way split of fp32 into hi/mid/lo bf16 (truncation; residuals exact).
__device__ __forceinline__ void split4(const f4 v, s4& h, s4& m, s4& l) {
  #pragma unroll
  for (int i = 0; i < 4; ++i) {
    float a = v[i];
    unsigned u = __builtin_bit_cast(unsigned, a);
    h[i] = (short)(u >> 16);
    float r1 = a - __builtin_bit_cast(float, u & 0xffff0000u);
    unsigned u1 = __builtin_bit_cast(unsigned, r1);
    m[i] = (short)(u1 >> 16);
    float r2 = r1 - __builtin_bit_cast(float, u1 & 0xffff0000u);
    l[i] = (short)(__builtin_bit_cast(unsigned, r2) >> 16);
  }
}

__device__ __forceinline__ void split8(const f4 v0, const f4 v1, s8& h, s8& m, s8& l) {
  s4 h0, m0, l0, h1, m1, l1;
  split4(v0, h0, m0, l0);
  split4(v1, h1, m1, l1);
  #pragma unroll
  for (int i = 0; i < 4; ++i) {
    h[i] = h0[i]; h[i + 4] = h1[i];
    m[i] = m0[i]; m[i + 4] = m1[i];
    l[i] = l0[i]; l[i + 4] = l1[i];
  }
}

// ---- kernel 1: split gate weights fp32 -> {hi,mid,lo} bf16 in d_ws --------
__global__ __launch_bounds__(256) void cvtW3(const float* __restrict__ Wf,
                                             u16* __restrict__ Wh,
                                             u16* __restrict__ Wm,
                                             u16* __restrict__ Wl) {
  int i = (blockIdx.x * 256 + threadIdx.x) * 8;  // 64 blocks cover 131072
  f4 v0 = *(const f4*)(Wf + i);
  f4 v1 = *(const f4*)(Wf + i + 4);
  s8 h, m, l;
  split8(v0, v1, h, m, l);
  *(s8*)((short*)Wh + i) = h;
  *(s8*)((short*)Wm + i) = m;
  *(s8*)((short*)Wl + i) = l;
}

// ---- kernel 2: fused gate ---------------------------------------------------
template <bool PRE>
__global__ __launch_bounds__(512, 2) void gateL(
    const float* __restrict__ X, const float* __restrict__ Wf,
    const u16* __restrict__ Wh, const u16* __restrict__ Wm,
    const u16* __restrict__ Wl, float* __restrict__ out) {
  __shared__ __align__(16) unsigned char smem[2 * BUFB];  // 96 KB

  const int tid = threadIdx.x;
  const int lane = tid & 63;
  const int w = tid >> 6;      // wave 0..7 -> owns tokens tok0 + w*16 ..
  const int ec = lane & 15;    // token row (A) / expert col (B)
  const int kg = lane >> 4;    // 0..3 (8 consecutive k)
  const int tok0 = blockIdx.x * 128;

  // A stream: this wave's 16 token rows
  const float* pA = X + (size_t)(tok0 + w * 16 + ec) * HD + kg * 8;

  // staging roles: wave w stages units u=2w, 2w+1; unit = (sh = u>>2, sg = u&3)
  const int u0 = 2 * w, u1 = 2 * w + 1;
  const int sh0 = u0 >> 2, sg0 = u0 & 3;
  const int sh1 = u1 >> 2, sg1 = u1 & 3;
  const size_t wsrc0 = (size_t)(sg0 * 16 + ec) * HD + sh0 * 32 + kg * 8;
  const size_t wsrc1 = (size_t)(sg1 * 16 + ec) * HD + sh1 * 32 + kg * 8;
  // LDS dst byte offset: ((sh*3+split)*4+sg)*1024 + lane*16   (+4096/split)
  const int sdst0 = (sh0 * 12 + sg0) * 1024 + lane * 16;
  const int sdst1 = (sh1 * 12 + sg1) * 1024 + lane * 16;

  accv acc[4];
  #pragma unroll
  for (int f = 0; f < 4; ++f) acc[f] = (accv){0.f, 0.f, 0.f, 0.f};

  f4 ar[SPC][2];  // A raw ring, 4-step lookahead (static indices only)

  // --- prologue: stage chunk 0 into buf0; prefetch A steps 0..3 ---
  {
    s8 th, tm, tl;
    f4 r0, r1;
    if constexpr (PRE) {
      th = *(const s8*)(Wh + wsrc0);
      tm = *(const s8*)(Wm + wsrc0);
      tl = *(const s8*)(Wl + wsrc0);
    } else {
      r0 = *(const f4*)(Wf + wsrc0);
      r1 = *(const f4*)(Wf + wsrc0 + 4);
      split8(r0, r1, th, tm, tl);
    }
    unsigned char* d = smem + sdst0;
    *(s8*)(d) = th;
    *(s8*)(d + 4096) = tm;
    *(s8*)(d + 8192) = tl;
    if constexpr (PRE) {
      th = *(const s8*)(Wh + wsrc1);
      tm = *(const s8*)(Wm + wsrc1);
      tl = *(const s8*)(Wl + wsrc1);
    } else {
      r0 = *(const f4*)(Wf + wsrc1);
      r1 = *(const f4*)(Wf + wsrc1 + 4);
      split8(r0, r1, th, tm, tl);
    }
    d = smem + sdst1;
    *(s8*)(d) = th;
    *(s8*)(d + 4096) = tm;
    *(s8*)(d + 8192) = tl;
  }
  #pragma unroll
  for (int st = 0; st < SPC; ++st) {
    ar[st][0] = *(const f4*)(pA + st * 32);
    ar[st][1] = *(const f4*)(pA + st * 32 + 4);
  }
  asm volatile("s_waitcnt lgkmcnt(0)");
  __builtin_amdgcn_s_barrier();
  __builtin_amdgcn_sched_barrier(0);

  // --- main loop: 16 chunks of K=128 (4 MFMA-steps each) ---
  for (int c = 0; c < NCH; ++c) {
    const unsigned char* rb = smem + (c & 1) * BUFB;
    unsigned char* wb = smem + ((c + 1) & 1) * BUFB;
    const bool do_stage = (c + 1 < NCH);

    // issue next-chunk B loads NOW (written to LDS after compute: T14 split)
    s8 th0, tm0, tl0, th1, tm1, tl1;
    f4 q00, q01, q10, q11;
    if (do_stage) {
      const size_t o0 = wsrc0 + (size_t)(c + 1) * 128;
      const size_t o1 = wsrc1 + (size_t)(c + 1) * 128;
      if constexpr (PRE) {
        th0 = *(const s8*)(Wh + o0);
        tm0 = *(const s8*)(Wm + o0);
        tl0 = *(const s8*)(Wl + o0);
        th1 = *(const s8*)(Wh + o1);
        tm1 = *(const s8*)(Wm + o1);
        tl1 = *(const s8*)(Wl + o1);
      } else {
        q00 = *(const f4*)(Wf + o0);
        q01 = *(const f4*)(Wf + o0 + 4);
        q10 = *(const f4*)(Wf + o1);
        q11 = *(const f4*)(Wf + o1 + 4);
      }
    }

    #pragma unroll
    for (int st = 0; st < SPC; ++st) {
      const int t = c * SPC + st;
      s8 ah, am, al;
      split8(ar[st][0], ar[st][1], ah, am, al);
      const int tn = (t + SPC < 64) ? (t + SPC) : 63;  // clamp; dup harmless
      ar[st][0] = *(const f4*)(pA + tn * 32);
      ar[st][1] = *(const f4*)(pA + tn * 32 + 4);
      #pragma unroll
      for (int f = 0; f < 4; ++f) {
        const unsigned char* bp = rb + st * 12288 + f * 1024 + lane * 16;
        s8 bh = *(const s8*)(bp);
        s8 bm = *(const s8*)(bp + 4096);
        s8 bl = *(const s8*)(bp + 8192);
        acc[f] = __builtin_amdgcn_mfma_f32_16x16x32_bf16(ah, bh, acc[f], 0, 0, 0);
        acc[f] = __builtin_amdgcn_mfma_f32_16x16x32_bf16(ah, bm, acc[f], 0, 0, 0);
        acc[f] = __builtin_amdgcn_mfma_f32_16x16x32_bf16(am, bh, acc[f], 0, 0, 0);
        acc[f] = __builtin_amdgcn_mfma_f32_16x16x32_bf16(ah, bl, acc[f], 0, 0, 0);
        acc[f] = __builtin_amdgcn_mfma_f32_16x16x32_bf16(al, bh, acc[f], 0, 0, 0);
        acc[f] = __builtin_amdgcn_mfma_f32_16x16x32_bf16(am, bm, acc[f], 0, 0, 0);
      }
    }

    // write staged B (loads have had 4 steps to land)
    if (do_stage) {
      if constexpr (!PRE) {
        split8(q00, q01, th0, tm0, tl0);
        split8(q10, q11, th1, tm1, tl1);
      }
      unsigned char* d = wb + sdst0;
      *(s8*)(d) = th0;
      *(s8*)(d + 4096) = tm0;
      *(s8*)(d + 8192) = tl0;
      d = wb + sdst1;
      *(s8*)(d) = th1;
      *(s8*)(d + 4096) = tm1;
      *(s8*)(d + 8192) = tl1;
    }
    // boundary: LDS-only drain; A vmcnt stream NEVER drained
    __builtin_amdgcn_sched_barrier(0);
    asm volatile("s_waitcnt lgkmcnt(0)");
    __builtin_amdgcn_s_barrier();
    __builtin_amdgcn_sched_barrier(0);
  }

  // --- epilogue: per-wave logit scatter (own region, no barrier needed) ---
  float* lf = (float*)smem + w * 1088;  // 16 tok x 68 floats
  #pragma unroll
  for (int f = 0; f < 4; ++f)
    #pragma unroll
    for (int r = 0; r < 4; ++r)
      lf[(kg * 4 + r) * 68 + f * 16 + ec] = acc[f][r];

  if (lane < 16) {
    float v[64];
    #pragma unroll
    for (int i = 0; i < 16; ++i) {
      f4 q = *(const f4*)(lf + lane * 68 + 4 * i);
      v[4 * i + 0] = q.x; v[4 * i + 1] = q.y;
      v[4 * i + 2] = q.z; v[4 * i + 3] = q.w;
    }
    // group maxes on logits (softmax monotonic -> same selection)
    float gm[8];
    #pragma unroll
    for (int g = 0; g < 8; ++g) {
      float mx = v[g * 8];
      #pragma unroll
      for (int j = 1; j < 8; ++j) mx = fmaxf(mx, v[g * 8 + j]);
      gm[g] = mx;
    }
    // top-3 groups, ties -> lowest index (matches lax.top_k)
    unsigned selmask = 0u;
    #pragma unroll
    for (int itg = 0; itg < 3; ++itg) {
      float best = gm[0];
      #pragma unroll
      for (int g = 1; g < 8; ++g) best = fmaxf(best, gm[g]);
      int bi = 7;
      #pragma unroll
      for (int g = 6; g >= 0; --g)
        if (gm[g] == best) bi = g;
      selmask |= (1u << bi);
      #pragma unroll
      for (int g = 0; g < 8; ++g) gm[g] = (g == bi) ? -3.0e38f : gm[g];
    }
    // top-6 of selected-group logits, branchless insertion network (desc)
    float t0 = -3.0e38f, t1 = -3.0e38f, t2 = -3.0e38f;
    float t3 = -3.0e38f, t4 = -3.0e38f, t5 = -3.0e38f;
    #pragma unroll
    for (int g = 0; g < 8; ++g) {
      const bool sel = (selmask >> g) & 1u;
      #pragma unroll
      for (int j = 0; j < 8; ++j) {
        float x = sel ? v[g * 8 + j] : -3.0e38f;
        float mm;
        mm = fmaxf(t0, x); x = fminf(t0, x); t0 = mm;
        mm = fmaxf(t1, x); x = fminf(t1, x); t1 = mm;
        mm = fmaxf(t2, x); x = fminf(t2, x); t2 = mm;
        mm = fmaxf(t3, x); x = fminf(t3, x); t3 = mm;
        mm = fmaxf(t4, x); x = fminf(t4, x); t4 = mm;
        t5 = fmaxf(t5, x);
      }
    }
    // normalized softmax over the selected 6 (global denom cancels exactly)
    float e0 = 1.0f;
    float e1 = __expf(t1 - t0);
    float e2 = __expf(t2 - t0);
    float e3 = __expf(t3 - t0);
    float e4 = __expf(t4 - t0);
    float e5 = __expf(t5 - t0);
    float sum = e0 + e1 + e2 + e3 + e4 + e5;
    float inv = 1.0f / sum;
    float* op = out + (size_t)(tok0 + w * 16 + lane) * 6;
    op[0] = e0 * inv; op[1] = e1 * inv; op[2] = e2 * inv;
    op[3] = e3 * inv; op[4] = e4 * inv; op[5] = e5 * inv;
  }
}

extern "C" void kernel_launch(void* const* d_in, const int* in_sizes, int n_in,
                              void* d_out, int out_size, void* d_ws, size_t ws_size,
                              hipStream_t stream) {
  const float* X = (const float*)d_in[0];
  const float* Wf = (const float*)d_in[1];
  float* out = (float*)d_out;
  const int T = in_sizes[0] / HD;  // 32768
  const int nblk = T / 128;        // 256 blocks of 512 threads (8 waves)

  const size_t need = (size_t)NE * HD * sizeof(u16);  // 256 KB per split
  if (ws_size >= 3 * need) {
    u16* Whi = (u16*)d_ws;
    u16* Wmi = Whi + (size_t)NE * HD;
    u16* Wlo = Wmi + (size_t)NE * HD;
    cvtW3<<<dim3(64), dim3(256), 0, stream>>>(Wf, Whi, Wmi, Wlo);
    gateL<true><<<dim3(nblk), dim3(512), 0, stream>>>(X, Wf, Whi, Wmi, Wlo, out);
  } else {
    gateL<false><<<dim3(nblk), dim3(512), 0, stream>>>(X, Wf, nullptr, nullptr, nullptr, out);
  }
}